// Round 2
// baseline (311.506 us; speedup 1.0000x reference)
//
#include <hip/hip_runtime.h>

#define BB 16
#define TT 2048
#define DD 768
#define HH 96

typedef __attribute__((ext_vector_type(8))) short bf16x8;
typedef __attribute__((ext_vector_type(4))) short bf16x4;
typedef __attribute__((ext_vector_type(4))) float f32x4;

static __device__ __forceinline__ unsigned short f2bf(float f) {
  unsigned u = __builtin_bit_cast(unsigned, f);
  u = (u + 0x7fffu + ((u >> 16) & 1u)) >> 16;   // round-to-nearest-even
  return (unsigned short)u;
}

// ---------------- W convert: Wt[w][n][k] bf16, w order = {q,k,v} ----------------
__global__ void wconv(const float* __restrict__ Wk, const float* __restrict__ Wq,
                      const float* __restrict__ Wv, unsigned short* __restrict__ Wt) {
  int idx = blockIdx.x * 256 + threadIdx.x;
  if (idx >= 3 * HH * DD) return;
  int w = idx / (HH * DD);
  int rem = idx - w * (HH * DD);
  int n = rem / DD;
  int k = rem - n * DD;
  const float* W = (w == 0) ? Wq : (w == 1) ? Wk : Wv;
  Wt[idx] = f2bf(W[k * HH + n]);
}

// ---------------- QKV projection ----------------
// grid 1024, block 384 (6 waves = {Q,K,V} x 2 row-groups of 16). Block = 32 rows.
// Each wave: acc[6] only (24 VGPR) -> high occupancy; waves sharing rows hit L1 on x.
__global__ __launch_bounds__(384) void qkv_proj(
    const float* __restrict__ x, const unsigned short* __restrict__ Wt,
    unsigned short* __restrict__ Qb, unsigned short* __restrict__ Kb,
    unsigned short* __restrict__ Vt) {
  __shared__ unsigned short vst[HH][40];   // 32-row V-tile transpose staging (+pad)
  const int tid = threadIdx.x;
  const int lane = tid & 63;
  const int w = tid >> 6;
  const int g = lane >> 4;
  const int m = lane & 15;
  const int outsel = w % 3;                // 0=Q 1=K 2=V
  const int rg = w / 3;                    // row-group
  const long r0 = (long)blockIdx.x * 32;
  const long rw = r0 + rg * 16;

  f32x4 acc[6];
#pragma unroll
  for (int nf = 0; nf < 6; ++nf) { acc[nf][0] = 0.f; acc[nf][1] = 0.f; acc[nf][2] = 0.f; acc[nf][3] = 0.f; }

  const float* xrow = x + (rw + m) * DD;
  const unsigned short* wbase = Wt + (long)outsel * HH * DD;
  for (int ks = 0; ks < DD / 32; ++ks) {
    const int k0 = ks * 32 + g * 8;
    f32x4 a0 = *(const f32x4*)(xrow + k0);
    f32x4 a1 = *(const f32x4*)(xrow + k0 + 4);
    bf16x8 a;
#pragma unroll
    for (int j = 0; j < 4; ++j) { a[j] = (short)f2bf(a0[j]); a[4 + j] = (short)f2bf(a1[j]); }
#pragma unroll
    for (int nf = 0; nf < 6; ++nf) {
      const bf16x8 wf = *(const bf16x8*)(wbase + (nf * 16 + m) * DD + k0);
      acc[nf] = __builtin_amdgcn_mfma_f32_16x16x32_bf16(a, wf, acc[nf], 0, 0, 0);
    }
  }
  if (outsel == 0) {
#pragma unroll
    for (int nf = 0; nf < 6; ++nf)
#pragma unroll
      for (int r = 0; r < 4; ++r)
        Qb[(rw + 4 * g + r) * HH + nf * 16 + m] = f2bf(acc[nf][r]);
  } else if (outsel == 1) {
#pragma unroll
    for (int nf = 0; nf < 6; ++nf)
#pragma unroll
      for (int r = 0; r < 4; ++r)
        Kb[(rw + 4 * g + r) * HH + nf * 16 + m] = f2bf(acc[nf][r]);
  } else {
#pragma unroll
    for (int nf = 0; nf < 6; ++nf)
#pragma unroll
      for (int r = 0; r < 4; ++r)
        vst[nf * 16 + m][rg * 16 + 4 * g + r] = f2bf(acc[nf][r]);
  }
  __syncthreads();
  // Vt[b][h][t] bf16: 96*32/8 = 384 chunks, exactly 1 per thread
  const int h = tid >> 2;
  const int t8 = (tid & 3) * 8;
  const int bidx = (int)(r0 >> 11);
  const int t0 = (int)(r0 & 2047);
  bf16x8 v = *(const bf16x8*)(&vst[h][t8]);
  *(bf16x8*)(Vt + ((long)(bidx * HH + h) * TT + t0 + t8)) = v;
}

// ---------------- flash attention, in-block KV-split ----------------
// grid (128, 16); block 256 = 4 waves. All waves share one 16-row q-tile; wave w
// processes KV tiles kt = w, w+4, ... independently (no barriers in main loop).
// S^T = K*Q^T (swapped) -> softmax in-lane + shfl_xor; P feeds PV from registers;
// V read directly from global Vt[b][h][t] (L2/L3-resident). One LDS merge at end.
__global__ __launch_bounds__(256) void attn(
    const unsigned short* __restrict__ Qb, const unsigned short* __restrict__ Kb,
    const unsigned short* __restrict__ Vt, float* __restrict__ out) {
  __shared__ float cm[3][64];
  __shared__ float cl[3][64];
  __shared__ float co[3][64][24];
  const int tid = threadIdx.x;
  const int lane = tid & 63;
  const int w = tid >> 6;
  const int g = lane >> 4;
  const int c = lane & 15;
  const int qt = (int)gridDim.x - 1 - (int)blockIdx.x;   // heavy tiles first
  const int b = blockIdx.y;
  const int q0 = qt * 16;
  const int lastkt = qt >> 2;                            // (qt*16+15)>>6
  const int nkv = lastkt + 1;

  bf16x8 qf[3];
  const unsigned short* qrow = Qb + (long)(b * TT + q0 + c) * HH;
#pragma unroll
  for (int ks = 0; ks < 3; ++ks) qf[ks] = *(const bf16x8*)(qrow + ks * 32 + g * 8);

  f32x4 o[6];
#pragma unroll
  for (int nf = 0; nf < 6; ++nf) { o[nf][0] = 0.f; o[nf][1] = 0.f; o[nf][2] = 0.f; o[nf][3] = 0.f; }
  float m_run = -1e30f, l_run = 0.f;
  const float SCL = 0.10206207261596577f * 1.44269504088896f;  // HS^-0.5 * log2(e)
  const unsigned short* vb = Vt + (long)b * HH * TT;
  const int qcol = q0 + c;

  for (int kt = w; kt < nkv; kt += 4) {
    const int kv0 = kt * 64;
    f32x4 s[4];
#pragma unroll
    for (int mf = 0; mf < 4; ++mf) { s[mf][0] = 0.f; s[mf][1] = 0.f; s[mf][2] = 0.f; s[mf][3] = 0.f; }
#pragma unroll
    for (int ks = 0; ks < 3; ++ks)
#pragma unroll
      for (int mf = 0; mf < 4; ++mf) {
        bf16x8 kfr = *(const bf16x8*)(Kb + (long)(b * TT + kv0 + mf * 16 + c) * HH + ks * 32 + g * 8);
        s[mf] = __builtin_amdgcn_mfma_f32_16x16x32_bf16(kfr, qf[ks], s[mf], 0, 0, 0);
      }

    // scale (log2-domain) + causal mask (only the diagonal tile needs it)
    float smax = -1e30f;
#pragma unroll
    for (int mf = 0; mf < 4; ++mf)
#pragma unroll
      for (int r = 0; r < 4; ++r) {
        float v = s[mf][r] * SCL;
        if (kt == lastkt && (kv0 + mf * 16 + 4 * g + r) > qcol) v = -1e30f;
        s[mf][r] = v;
        smax = fmaxf(smax, v);
      }
    smax = fmaxf(smax, __shfl_xor(smax, 16));
    smax = fmaxf(smax, __shfl_xor(smax, 32));
    const float m_new = fmaxf(m_run, smax);
    const float corr = __builtin_amdgcn_exp2f(m_run - m_new);
    float rsum = 0.f;
    unsigned short pb[4][4];
#pragma unroll
    for (int mf = 0; mf < 4; ++mf)
#pragma unroll
      for (int r = 0; r < 4; ++r) {
        float p = __builtin_amdgcn_exp2f(s[mf][r] - m_new);
        rsum += p;
        pb[mf][r] = f2bf(p);
      }
    rsum += __shfl_xor(rsum, 16);
    rsum += __shfl_xor(rsum, 32);
    l_run = l_run * corr + rsum;
    m_run = m_new;
#pragma unroll
    for (int r = 0; r < 4; ++r) {          // rescale O rows (stats for q=4g+r live at lane 4g+r)
      float cr = __shfl(corr, 4 * g + r);
#pragma unroll
      for (int nf = 0; nf < 6; ++nf) o[nf][r] *= cr;
    }
    // PV: A-slot (g,i) -> kv = 4g + (i&3) + 16*(2kf + (i>>2)); V loaded with same map
#pragma unroll
    for (int kf = 0; kf < 2; ++kf) {
      bf16x8 a;
#pragma unroll
      for (int i = 0; i < 8; ++i) a[i] = (short)pb[2 * kf + (i >> 2)][i & 3];
#pragma unroll
      for (int nf = 0; nf < 6; ++nf) {
        const unsigned short* vrow = vb + (long)(nf * 16 + c) * TT + kv0 + kf * 32 + 4 * g;
        bf16x4 lo = *(const bf16x4*)(vrow);
        bf16x4 hi = *(const bf16x4*)(vrow + 16);
        bf16x8 vf = __builtin_shufflevector(lo, hi, 0, 1, 2, 3, 4, 5, 6, 7);
        o[nf] = __builtin_amdgcn_mfma_f32_16x16x32_bf16(a, vf, o[nf], 0, 0, 0);
      }
    }
  }

  // -------- merge the 4 per-wave partials --------
  if (w) {
    cm[w - 1][lane] = m_run;
    cl[w - 1][lane] = l_run;
#pragma unroll
    for (int nf = 0; nf < 6; ++nf)
#pragma unroll
      for (int r = 0; r < 4; ++r) co[w - 1][lane][nf * 4 + r] = o[nf][r];
  }
  __syncthreads();
  if (w == 0) {
    float m_f = m_run, l_f = l_run;
#pragma unroll
    for (int j = 0; j < 3; ++j) {
      float mj = cm[j][lane], lj = cl[j][lane];
      float mn = fmaxf(m_f, mj);
      float c0 = __builtin_amdgcn_exp2f(m_f - mn);
      float cj = __builtin_amdgcn_exp2f(mj - mn);
      l_f = l_f * c0 + lj * cj;
      m_f = mn;
#pragma unroll
      for (int r = 0; r < 4; ++r) {
        float c0r = __shfl(c0, 4 * g + r);
        float cjr = __shfl(cj, 4 * g + r);
#pragma unroll
        for (int nf = 0; nf < 6; ++nf)
          o[nf][r] = o[nf][r] * c0r + co[j][lane][nf * 4 + r] * cjr;
      }
    }
    const float inv = 1.0f / l_f;
#pragma unroll
    for (int r = 0; r < 4; ++r) {
      float ivr = __shfl(inv, 4 * g + r);
      long orow = (long)(b * TT + q0 + 4 * g + r) * HH;
#pragma unroll
      for (int nf = 0; nf < 6; ++nf) out[orow + nf * 16 + c] = o[nf][r] * ivr;
    }
  }
}

extern "C" void kernel_launch(void* const* d_in, const int* in_sizes, int n_in,
                              void* d_out, int out_size, void* d_ws, size_t ws_size,
                              hipStream_t stream) {
  const float* x  = (const float*)d_in[0];
  const float* Wk = (const float*)d_in[1];
  const float* Wq = (const float*)d_in[2];
  const float* Wv = (const float*)d_in[3];
  float* out = (float*)d_out;

  unsigned short* Wt = (unsigned short*)d_ws;        // 3*96*768 bf16 = 442 KB
  unsigned short* Qb = Wt + 3 * HH * DD;             // [B*T][96] bf16
  unsigned short* Kb = Qb + (long)BB * TT * HH;      // [B*T][96] bf16
  unsigned short* Vt = Kb + (long)BB * TT * HH;      // [B][96][T] bf16 (transposed)

  wconv<<<dim3((3 * HH * DD + 255) / 256), dim3(256), 0, stream>>>(Wk, Wq, Wv, Wt);
  qkv_proj<<<dim3(BB * TT / 32), dim3(384), 0, stream>>>(x, Wt, Qb, Kb, Vt);
  attn<<<dim3(TT / 16, BB), dim3(256), 0, stream>>>(Qb, Kb, Vt, out);
}

// Round 3
// 191.433 us; speedup vs baseline: 1.6272x; 1.6272x over previous
//
#include <hip/hip_runtime.h>
#include <utility>

#define BB 16
#define TT 2048
#define DD 768
#define HH 96

typedef __attribute__((ext_vector_type(8))) short bf16x8;
typedef __attribute__((ext_vector_type(4))) short bf16x4;
typedef __attribute__((ext_vector_type(4))) float f32x4;

static __device__ __forceinline__ unsigned short f2bf(float f) {
  unsigned u = __builtin_bit_cast(unsigned, f);
  u = (u + 0x7fffu + ((u >> 16) & 1u)) >> 16;   // round-to-nearest-even
  return (unsigned short)u;
}

// ---------------- W convert: Wt[w][n][k] bf16, w order = {q,k,v} ----------------
__global__ void wconv(const float* __restrict__ Wk, const float* __restrict__ Wq,
                      const float* __restrict__ Wv, unsigned short* __restrict__ Wt) {
  int idx = blockIdx.x * 256 + threadIdx.x;
  if (idx >= 3 * HH * DD) return;
  int w = idx / (HH * DD);
  int rem = idx - w * (HH * DD);
  int n = rem / DD;
  int k = rem - n * DD;
  const float* W = (w == 0) ? Wq : (w == 1) ? Wk : Wv;
  Wt[idx] = f2bf(W[k * HH + n]);
}

// ---------------- QKV projection ----------------
// grid 1024, block 384 (6 waves = {Q,K,V} x 2 row-groups of 16). K-loop unrolled x2
// so 16 loads issue per iteration before the MFMAs (MLP).
__global__ __launch_bounds__(384) void qkv_proj(
    const float* __restrict__ x, const unsigned short* __restrict__ Wt,
    unsigned short* __restrict__ Qb, unsigned short* __restrict__ Kb,
    unsigned short* __restrict__ Vt) {
  __shared__ unsigned short vst[HH][40];   // 32-row V-tile transpose staging (+pad)
  const int tid = threadIdx.x;
  const int lane = tid & 63;
  const int w = tid >> 6;
  const int g = lane >> 4;
  const int m = lane & 15;
  const int outsel = w % 3;                // 0=Q 1=K 2=V
  const int rg = w / 3;                    // row-group
  const long r0 = (long)blockIdx.x * 32;
  const long rw = r0 + rg * 16;

  f32x4 acc[6];
#pragma unroll
  for (int nf = 0; nf < 6; ++nf) { acc[nf][0] = 0.f; acc[nf][1] = 0.f; acc[nf][2] = 0.f; acc[nf][3] = 0.f; }

  const float* xrow = x + (rw + m) * DD;
  const unsigned short* wbase = Wt + (long)outsel * HH * DD;
  for (int ks = 0; ks < DD / 64; ++ks) {
    const int k0 = ks * 64 + g * 8;
    f32x4 a00 = *(const f32x4*)(xrow + k0);
    f32x4 a01 = *(const f32x4*)(xrow + k0 + 4);
    f32x4 a10 = *(const f32x4*)(xrow + k0 + 32);
    f32x4 a11 = *(const f32x4*)(xrow + k0 + 36);
    bf16x8 wv0[6], wv1[6];
#pragma unroll
    for (int nf = 0; nf < 6; ++nf) {
      wv0[nf] = *(const bf16x8*)(wbase + (nf * 16 + m) * DD + k0);
      wv1[nf] = *(const bf16x8*)(wbase + (nf * 16 + m) * DD + k0 + 32);
    }
    bf16x8 a0, a1;
#pragma unroll
    for (int j = 0; j < 4; ++j) {
      a0[j] = (short)f2bf(a00[j]); a0[4 + j] = (short)f2bf(a01[j]);
      a1[j] = (short)f2bf(a10[j]); a1[4 + j] = (short)f2bf(a11[j]);
    }
#pragma unroll
    for (int nf = 0; nf < 6; ++nf) {
      acc[nf] = __builtin_amdgcn_mfma_f32_16x16x32_bf16(a0, wv0[nf], acc[nf], 0, 0, 0);
      acc[nf] = __builtin_amdgcn_mfma_f32_16x16x32_bf16(a1, wv1[nf], acc[nf], 0, 0, 0);
    }
  }
  if (outsel == 0) {
#pragma unroll
    for (int nf = 0; nf < 6; ++nf)
#pragma unroll
      for (int r = 0; r < 4; ++r)
        Qb[(rw + 4 * g + r) * HH + nf * 16 + m] = f2bf(acc[nf][r]);
  } else if (outsel == 1) {
#pragma unroll
    for (int nf = 0; nf < 6; ++nf)
#pragma unroll
      for (int r = 0; r < 4; ++r)
        Kb[(rw + 4 * g + r) * HH + nf * 16 + m] = f2bf(acc[nf][r]);
  } else {
#pragma unroll
    for (int nf = 0; nf < 6; ++nf)
#pragma unroll
      for (int r = 0; r < 4; ++r)
        vst[nf * 16 + m][rg * 16 + 4 * g + r] = f2bf(acc[nf][r]);
  }
  __syncthreads();
  const int h = tid >> 2;
  const int t8 = (tid & 3) * 8;
  const int bidx = (int)(r0 >> 11);
  const int t0 = (int)(r0 & 2047);
  bf16x8 v = *(const bf16x8*)(&vst[h][t8]);
  *(bf16x8*)(Vt + ((long)(bidx * HH + h) * TT + t0 + t8)) = v;
}

// ---------------- flash attention, async 2-phase pipeline ----------------
// Block = 4 waves, 64-row q-tile, interleaved q-map (q = q0 + 4*j + w, j = local).
// K/V tiles reg-staged (global->reg issued one tile early; reg->LDS one iter later),
// double-buffered padded LDS (conflict-free reads), ONE raw barrier per tile.
__global__ __launch_bounds__(256, 2) void attn(
    const unsigned short* __restrict__ Qb, const unsigned short* __restrict__ Kb,
    const unsigned short* __restrict__ Vt, float* __restrict__ out) {
  __shared__ unsigned short Klds[2][64 * 104];   // 64 rows x (96 data + 8 pad)
  __shared__ unsigned short Vlds[2][96 * 72];    // 96 rows x (64 data + 8 pad)
  const int tid = threadIdx.x;
  const int lane = tid & 63;
  const int w = tid >> 6;
  const int g = lane >> 4;
  const int c = lane & 15;

  // block -> (batch, q-tile): XCD owns 2 batches (blk%8 -> XCD heuristic); heavy qt first
  const int blk = (int)blockIdx.x;
  const int b = ((blk & 7) << 1) + ((blk >> 3) & 1);
  const int qt = 31 - (blk >> 4);
  const int q0 = qt * 64;
  const int lastkt = qt;

  // Q fragments: lane c owns q-row q0 + 4c + w
  bf16x8 qf[3];
  {
    const unsigned short* qrow = Qb + ((long)b * TT + q0 + 4 * c + w) * HH;
#pragma unroll
    for (int ks = 0; ks < 3; ++ks) qf[ks] = *(const bf16x8*)(qrow + ks * 32 + g * 8);
  }

  const unsigned short* Kbase = Kb + (long)b * TT * HH;
  const unsigned short* Vbase = Vt + (long)b * HH * TT;

  f32x4 o[6];
#pragma unroll
  for (int nf = 0; nf < 6; ++nf) { o[nf][0] = 0.f; o[nf][1] = 0.f; o[nf][2] = 0.f; o[nf][3] = 0.f; }
  float m_run = -1e30f, l_run = 0.f;
  const float SCL = 0.10206207261596577f * 1.44269504088896f;  // HS^-0.5 * log2(e)

  bf16x8 kreg[2][3], vreg[2][3];

  auto issue = [&](auto PC, int t) {       // global -> reg for tile t
    constexpr int P = decltype(PC)::value;
    if (t <= lastkt) {
      const unsigned short* ksrc = Kbase + (long)t * 64 * HH;
#pragma unroll
      for (int i = 0; i < 3; ++i) kreg[P][i] = *(const bf16x8*)(ksrc + (tid + i * 256) * 8);
#pragma unroll
      for (int i = 0; i < 3; ++i) {
        int j = tid + i * 256;
        vreg[P][i] = *(const bf16x8*)(Vbase + (long)(j >> 3) * TT + t * 64 + (j & 7) * 8);
      }
    }
  };
  auto lwrite = [&](auto PC, int t) {      // reg -> LDS for tile t
    constexpr int P = decltype(PC)::value;
    if (t <= lastkt) {
#pragma unroll
      for (int i = 0; i < 3; ++i) {
        int j = tid + i * 256;
        int row = j / 12, gs = j - row * 12;
        *(bf16x8*)(&Klds[P][row * 104 + gs * 8]) = kreg[P][i];
      }
#pragma unroll
      for (int i = 0; i < 3; ++i) {
        int j = tid + i * 256;
        *(bf16x8*)(&Vlds[P][(j >> 3) * 72 + (j & 7) * 8]) = vreg[P][i];
      }
    }
  };
  auto bar = [&]() {
    asm volatile("s_waitcnt lgkmcnt(0)" ::: "memory");
    __builtin_amdgcn_s_barrier();
    __builtin_amdgcn_sched_barrier(0);
  };
  auto compute = [&](auto PC, int t) {
    constexpr int P = decltype(PC)::value;
    const int kv0 = t * 64;
    f32x4 s[4];
#pragma unroll
    for (int mf = 0; mf < 4; ++mf) { s[mf][0] = 0.f; s[mf][1] = 0.f; s[mf][2] = 0.f; s[mf][3] = 0.f; }
#pragma unroll
    for (int ks = 0; ks < 3; ++ks) {
      bf16x8 kb_[4];
#pragma unroll
      for (int mf = 0; mf < 4; ++mf)
        kb_[mf] = *(const bf16x8*)(&Klds[P][(mf * 16 + c) * 104 + ks * 32 + g * 8]);
#pragma unroll
      for (int mf = 0; mf < 4; ++mf)
        s[mf] = __builtin_amdgcn_mfma_f32_16x16x32_bf16(kb_[mf], qf[ks], s[mf], 0, 0, 0);
    }
    const int qcol = q0 + 4 * c + w;
    const bool diag = (t == lastkt);
    float smax = -1e30f;
#pragma unroll
    for (int mf = 0; mf < 4; ++mf)
#pragma unroll
      for (int r = 0; r < 4; ++r) {
        float v = s[mf][r] * SCL;
        if (diag && (kv0 + mf * 16 + 4 * g + r) > qcol) v = -1e30f;
        s[mf][r] = v;
        smax = fmaxf(smax, v);
      }
    smax = fmaxf(smax, __shfl_xor(smax, 16));
    smax = fmaxf(smax, __shfl_xor(smax, 32));
    const float m_new = fmaxf(m_run, smax);
    const float corr = __builtin_amdgcn_exp2f(m_run - m_new);
    float rsum = 0.f;
    unsigned short pb[4][4];
#pragma unroll
    for (int mf = 0; mf < 4; ++mf)
#pragma unroll
      for (int r = 0; r < 4; ++r) {
        float p = __builtin_amdgcn_exp2f(s[mf][r] - m_new);
        rsum += p;
        pb[mf][r] = f2bf(p);
      }
    rsum += __shfl_xor(rsum, 16);
    rsum += __shfl_xor(rsum, 32);
    l_run = l_run * corr + rsum;
    m_run = m_new;
#pragma unroll
    for (int r = 0; r < 4; ++r) {
      float cr = __shfl(corr, 4 * g + r);
#pragma unroll
      for (int nf = 0; nf < 6; ++nf) o[nf][r] *= cr;
    }
    // PV: A-slot (g,i) -> kv = 4g + (i&3) + 16*(2kf + (i>>2)); V read with same map
#pragma unroll
    for (int kf = 0; kf < 2; ++kf) {
      bf16x8 a;
#pragma unroll
      for (int i = 0; i < 8; ++i) a[i] = (short)pb[2 * kf + (i >> 2)][i & 3];
#pragma unroll
      for (int nf = 0; nf < 6; ++nf) {
        const unsigned short* vr = &Vlds[P][(nf * 16 + c) * 72 + kf * 32 + 4 * g];
        bf16x4 lo = *(const bf16x4*)(vr);
        bf16x4 hi = *(const bf16x4*)(vr + 16);
        bf16x8 vf = __builtin_shufflevector(lo, hi, 0, 1, 2, 3, 4, 5, 6, 7);
        o[nf] = __builtin_amdgcn_mfma_f32_16x16x32_bf16(a, vf, o[nf], 0, 0, 0);
      }
    }
  };

  std::integral_constant<int, 0> P0;
  std::integral_constant<int, 1> P1;

  // prologue: tile0 -> regs0, tile1 -> regs1, write tile0 to LDS buf0
  issue(P0, 0);
  issue(P1, 1);
  lwrite(P0, 0);
  bar();

  for (int t = 0; t <= lastkt; t += 2) {
    issue(P0, t + 2);        // start next-next loads early (hide under compute)
    compute(P0, t);
    lwrite(P1, t + 1);       // tile t+1 regs -> buf1 (free since last barrier)
    bar();
    if (t + 1 <= lastkt) {
      issue(P1, t + 3);
      compute(P1, t + 1);
      lwrite(P0, t + 2);
      bar();
    }
  }

  const float inv = 1.0f / l_run;
#pragma unroll
  for (int r = 0; r < 4; ++r) {
    float ivr = __shfl(inv, 4 * g + r);
    long orow = ((long)b * TT + q0 + 16 * g + 4 * r + w) * HH;
#pragma unroll
    for (int nf = 0; nf < 6; ++nf) out[orow + nf * 16 + c] = o[nf][r] * ivr;
  }
}

extern "C" void kernel_launch(void* const* d_in, const int* in_sizes, int n_in,
                              void* d_out, int out_size, void* d_ws, size_t ws_size,
                              hipStream_t stream) {
  const float* x  = (const float*)d_in[0];
  const float* Wk = (const float*)d_in[1];
  const float* Wq = (const float*)d_in[2];
  const float* Wv = (const float*)d_in[3];
  float* out = (float*)d_out;

  unsigned short* Wt = (unsigned short*)d_ws;        // 3*96*768 bf16 = 442 KB
  unsigned short* Qb = Wt + 3 * HH * DD;             // [B*T][96] bf16
  unsigned short* Kb = Qb + (long)BB * TT * HH;      // [B*T][96] bf16
  unsigned short* Vt = Kb + (long)BB * TT * HH;      // [B][96][T] bf16 (transposed)

  wconv<<<dim3((3 * HH * DD + 255) / 256), dim3(256), 0, stream>>>(Wk, Wq, Wv, Wt);
  qkv_proj<<<dim3(BB * TT / 32), dim3(384), 0, stream>>>(x, Wt, Qb, Kb, Vt);
  attn<<<dim3(512), dim3(256), 0, stream>>>(Qb, Kb, Vt, out);
}

// Round 4
// 123.893 us; speedup vs baseline: 2.5143x; 1.5451x over previous
//
#include <hip/hip_runtime.h>
#include <utility>

#define BB 16
#define TT 2048
#define DD 768
#define HH 96

typedef __attribute__((ext_vector_type(8))) short bf16x8;
typedef __attribute__((ext_vector_type(4))) short bf16x4;
typedef __attribute__((ext_vector_type(4))) float f32x4;

static __device__ __forceinline__ unsigned short f2bf(float f) {
  unsigned u = __builtin_bit_cast(unsigned, f);
  u = (u + 0x7fffu + ((u >> 16) & 1u)) >> 16;   // round-to-nearest-even
  return (unsigned short)u;
}

// ---------------- W convert: Wt[w][n][k] bf16, w order = {q,k,v} ----------------
__global__ void wconv(const float* __restrict__ Wk, const float* __restrict__ Wq,
                      const float* __restrict__ Wv, unsigned short* __restrict__ Wt) {
  int idx = blockIdx.x * 256 + threadIdx.x;
  if (idx >= 3 * HH * DD) return;
  int w = idx / (HH * DD);
  int rem = idx - w * (HH * DD);
  int n = rem / DD;
  int k = rem - n * DD;
  const float* W = (w == 0) ? Wq : (w == 1) ? Wk : Wv;
  Wt[idx] = f2bf(W[k * HH + n]);
}

// ---------------- QKV projection: LDS-staged pipelined GEMM ----------------
// grid 512 (64 rows each), block 384 = 6 waves ({Q,K,V} x 2 row-groups of 32).
// Per K-step (BK=64): W-slab [288][64] bf16 staged via global_load_lds (double-
// buffered, XOR-swizzled through pre-swizzled source), x prefetched to regs one
// step ahead. One vmcnt(0)+barrier per step.
__global__ __launch_bounds__(384, 3) void qkv_proj(
    const float* __restrict__ x, const unsigned short* __restrict__ Wt,
    unsigned short* __restrict__ Qb, unsigned short* __restrict__ Kb,
    unsigned short* __restrict__ Vt) {
  __shared__ unsigned short Wlds[2][288 * 64];   // 2 x 36 KB
  const int tid = threadIdx.x;
  const int lane = tid & 63;
  const int w = tid >> 6;
  const int g = lane >> 4;
  const int m = lane & 15;
  const int outsel = w % 3;                // 0=Q 1=K 2=V
  const int rg = w / 3;                    // row-group (32 rows each)
  const long r0 = (long)blockIdx.x * 64;
  const long rw = r0 + rg * 32;

  f32x4 acc[2][6];
#pragma unroll
  for (int u = 0; u < 2; ++u)
#pragma unroll
    for (int nf = 0; nf < 6; ++nf) { acc[u][nf][0] = 0.f; acc[u][nf][1] = 0.f; acc[u][nf][2] = 0.f; acc[u][nf][3] = 0.f; }

  f32x4 xa[2][2][2][2];                    // [buf][u][ks2][half]

  // stage W-slab for K-step t into Wlds[P]; source pre-swizzled so that the
  // swizzled ds_read (short idx ^ ((m&7)<<3)) sees logical data.
  auto stage = [&](auto PC, int t) {
    constexpr int P = decltype(PC)::value;
#pragma unroll
    for (int i = 0; i < 6; ++i) {
      const int j0 = (w * 6 + i) * 64;     // granule base (uniform per wave)
      const int j = j0 + lane;
      const int r = j >> 3, s = j & 7;
      const unsigned short* src = Wt + r * DD + t * 64 + ((s ^ (r & 7)) * 8);
      __builtin_amdgcn_global_load_lds(
          (const __attribute__((address_space(1))) void*)src,
          (__attribute__((address_space(3))) void*)(&Wlds[P][j0 * 8]), 16, 0, 0);
    }
  };
  auto loadx = [&](auto PC, int t) {
    constexpr int P = decltype(PC)::value;
#pragma unroll
    for (int u = 0; u < 2; ++u) {
      const float* xr = x + (rw + u * 16 + m) * DD + t * 64 + g * 8;
#pragma unroll
      for (int ks2 = 0; ks2 < 2; ++ks2) {
        xa[P][u][ks2][0] = *(const f32x4*)(xr + ks2 * 32);
        xa[P][u][ks2][1] = *(const f32x4*)(xr + ks2 * 32 + 4);
      }
    }
  };
  auto barfull = [&]() {
    asm volatile("s_waitcnt vmcnt(0) lgkmcnt(0)" ::: "memory");
    __builtin_amdgcn_s_barrier();
    __builtin_amdgcn_sched_barrier(0);
  };
  auto compute = [&](auto PC) {
    constexpr int P = decltype(PC)::value;
#pragma unroll
    for (int ks2 = 0; ks2 < 2; ++ks2) {
      bf16x8 wf[6];
#pragma unroll
      for (int nf = 0; nf < 6; ++nf) {
        const int ridx = outsel * 96 + nf * 16 + m;
        const int sidx = (ridx * 64 + ks2 * 32 + g * 8) ^ ((m & 7) << 3);
        wf[nf] = *(const bf16x8*)(&Wlds[P][sidx]);
      }
      bf16x8 a[2];
#pragma unroll
      for (int u = 0; u < 2; ++u) {
        f32x4 lo = xa[P][u][ks2][0], hi = xa[P][u][ks2][1];
#pragma unroll
        for (int jj = 0; jj < 4; ++jj) { a[u][jj] = (short)f2bf(lo[jj]); a[u][4 + jj] = (short)f2bf(hi[jj]); }
      }
#pragma unroll
      for (int u = 0; u < 2; ++u)
#pragma unroll
        for (int nf = 0; nf < 6; ++nf)
          acc[u][nf] = __builtin_amdgcn_mfma_f32_16x16x32_bf16(a[u], wf[nf], acc[u][nf], 0, 0, 0);
    }
  };

  std::integral_constant<int, 0> P0;
  std::integral_constant<int, 1> P1;

  stage(P0, 0); loadx(P0, 0);
  barfull();
#pragma unroll
  for (int t = 0; t < 12; t += 2) {
    stage(P1, t + 1); loadx(P1, t + 1);    // issue next-step loads before compute
    compute(P0);
    barfull();
    if (t + 2 < 12) { stage(P0, t + 2); loadx(P0, t + 2); }
    compute(P1);
    if (t + 2 < 12) barfull();
  }

  // ---------------- epilogue ----------------
  unsigned short (*vst)[72] = (unsigned short (*)[72])(&Wlds[0][0]);  // alias (buf0 dead)
  if (outsel == 0) {
#pragma unroll
    for (int u = 0; u < 2; ++u)
#pragma unroll
      for (int nf = 0; nf < 6; ++nf)
#pragma unroll
        for (int r = 0; r < 4; ++r)
          Qb[(rw + u * 16 + 4 * g + r) * HH + nf * 16 + m] = f2bf(acc[u][nf][r]);
  } else if (outsel == 1) {
#pragma unroll
    for (int u = 0; u < 2; ++u)
#pragma unroll
      for (int nf = 0; nf < 6; ++nf)
#pragma unroll
        for (int r = 0; r < 4; ++r)
          Kb[(rw + u * 16 + 4 * g + r) * HH + nf * 16 + m] = f2bf(acc[u][nf][r]);
  } else {
#pragma unroll
    for (int u = 0; u < 2; ++u)
#pragma unroll
      for (int nf = 0; nf < 6; ++nf)
#pragma unroll
        for (int r = 0; r < 4; ++r)
          vst[nf * 16 + m][rg * 32 + u * 16 + 4 * g + r] = f2bf(acc[u][nf][r]);
  }
  __syncthreads();
  // Vt[b][h][t] bf16: 96*64/8 = 768 chunks, 2 per thread
  const int bidx = (int)(r0 >> 11);
  const int t0 = (int)(r0 & 2047);
#pragma unroll
  for (int jj = 0; jj < 2; ++jj) {
    int flat = tid + jj * 384;
    int h = flat >> 3;
    int t8 = (flat & 7) * 8;
    bf16x8 v = *(const bf16x8*)(&vst[h][t8]);
    *(bf16x8*)(Vt + ((long)(bidx * HH + h) * TT + t0 + t8)) = v;
  }
}

// ---------------- flash attention, async 2-phase pipeline (unchanged) ----------------
__global__ __launch_bounds__(256, 2) void attn(
    const unsigned short* __restrict__ Qb, const unsigned short* __restrict__ Kb,
    const unsigned short* __restrict__ Vt, float* __restrict__ out) {
  __shared__ unsigned short Klds[2][64 * 104];   // 64 rows x (96 data + 8 pad)
  __shared__ unsigned short Vlds[2][96 * 72];    // 96 rows x (64 data + 8 pad)
  const int tid = threadIdx.x;
  const int lane = tid & 63;
  const int w = tid >> 6;
  const int g = lane >> 4;
  const int c = lane & 15;

  const int blk = (int)blockIdx.x;
  const int b = ((blk & 7) << 1) + ((blk >> 3) & 1);
  const int qt = 31 - (blk >> 4);
  const int q0 = qt * 64;
  const int lastkt = qt;

  bf16x8 qf[3];
  {
    const unsigned short* qrow = Qb + ((long)b * TT + q0 + 4 * c + w) * HH;
#pragma unroll
    for (int ks = 0; ks < 3; ++ks) qf[ks] = *(const bf16x8*)(qrow + ks * 32 + g * 8);
  }

  const unsigned short* Kbase = Kb + (long)b * TT * HH;
  const unsigned short* Vbase = Vt + (long)b * HH * TT;

  f32x4 o[6];
#pragma unroll
  for (int nf = 0; nf < 6; ++nf) { o[nf][0] = 0.f; o[nf][1] = 0.f; o[nf][2] = 0.f; o[nf][3] = 0.f; }
  float m_run = -1e30f, l_run = 0.f;
  const float SCL = 0.10206207261596577f * 1.44269504088896f;  // HS^-0.5 * log2(e)

  bf16x8 kreg[2][3], vreg[2][3];

  auto issue = [&](auto PC, int t) {
    constexpr int P = decltype(PC)::value;
    if (t <= lastkt) {
      const unsigned short* ksrc = Kbase + (long)t * 64 * HH;
#pragma unroll
      for (int i = 0; i < 3; ++i) kreg[P][i] = *(const bf16x8*)(ksrc + (tid + i * 256) * 8);
#pragma unroll
      for (int i = 0; i < 3; ++i) {
        int j = tid + i * 256;
        vreg[P][i] = *(const bf16x8*)(Vbase + (long)(j >> 3) * TT + t * 64 + (j & 7) * 8);
      }
    }
  };
  auto lwrite = [&](auto PC, int t) {
    constexpr int P = decltype(PC)::value;
    if (t <= lastkt) {
#pragma unroll
      for (int i = 0; i < 3; ++i) {
        int j = tid + i * 256;
        int row = j / 12, gs = j - row * 12;
        *(bf16x8*)(&Klds[P][row * 104 + gs * 8]) = kreg[P][i];
      }
#pragma unroll
      for (int i = 0; i < 3; ++i) {
        int j = tid + i * 256;
        *(bf16x8*)(&Vlds[P][(j >> 3) * 72 + (j & 7) * 8]) = vreg[P][i];
      }
    }
  };
  auto bar = [&]() {
    asm volatile("s_waitcnt lgkmcnt(0)" ::: "memory");
    __builtin_amdgcn_s_barrier();
    __builtin_amdgcn_sched_barrier(0);
  };
  auto compute = [&](auto PC, int t) {
    constexpr int P = decltype(PC)::value;
    const int kv0 = t * 64;
    f32x4 s[4];
#pragma unroll
    for (int mf = 0; mf < 4; ++mf) { s[mf][0] = 0.f; s[mf][1] = 0.f; s[mf][2] = 0.f; s[mf][3] = 0.f; }
#pragma unroll
    for (int ks = 0; ks < 3; ++ks) {
      bf16x8 kb_[4];
#pragma unroll
      for (int mf = 0; mf < 4; ++mf)
        kb_[mf] = *(const bf16x8*)(&Klds[P][(mf * 16 + c) * 104 + ks * 32 + g * 8]);
#pragma unroll
      for (int mf = 0; mf < 4; ++mf)
        s[mf] = __builtin_amdgcn_mfma_f32_16x16x32_bf16(kb_[mf], qf[ks], s[mf], 0, 0, 0);
    }
    const int qcol = q0 + 4 * c + w;
    const bool diag = (t == lastkt);
    float smax = -1e30f;
#pragma unroll
    for (int mf = 0; mf < 4; ++mf)
#pragma unroll
      for (int r = 0; r < 4; ++r) {
        float v = s[mf][r] * SCL;
        if (diag && (kv0 + mf * 16 + 4 * g + r) > qcol) v = -1e30f;
        s[mf][r] = v;
        smax = fmaxf(smax, v);
      }
    smax = fmaxf(smax, __shfl_xor(smax, 16));
    smax = fmaxf(smax, __shfl_xor(smax, 32));
    const float m_new = fmaxf(m_run, smax);
    const float corr = __builtin_amdgcn_exp2f(m_run - m_new);
    float rsum = 0.f;
    unsigned short pb[4][4];
#pragma unroll
    for (int mf = 0; mf < 4; ++mf)
#pragma unroll
      for (int r = 0; r < 4; ++r) {
        float p = __builtin_amdgcn_exp2f(s[mf][r] - m_new);
        rsum += p;
        pb[mf][r] = f2bf(p);
      }
    rsum += __shfl_xor(rsum, 16);
    rsum += __shfl_xor(rsum, 32);
    l_run = l_run * corr + rsum;
    m_run = m_new;
#pragma unroll
    for (int r = 0; r < 4; ++r) {
      float cr = __shfl(corr, 4 * g + r);
#pragma unroll
      for (int nf = 0; nf < 6; ++nf) o[nf][r] *= cr;
    }
#pragma unroll
    for (int kf = 0; kf < 2; ++kf) {
      bf16x8 a;
#pragma unroll
      for (int i = 0; i < 8; ++i) a[i] = (short)pb[2 * kf + (i >> 2)][i & 3];
#pragma unroll
      for (int nf = 0; nf < 6; ++nf) {
        const unsigned short* vr = &Vlds[P][(nf * 16 + c) * 72 + kf * 32 + 4 * g];
        bf16x4 lo = *(const bf16x4*)(vr);
        bf16x4 hi = *(const bf16x4*)(vr + 16);
        bf16x8 vf = __builtin_shufflevector(lo, hi, 0, 1, 2, 3, 4, 5, 6, 7);
        o[nf] = __builtin_amdgcn_mfma_f32_16x16x32_bf16(a, vf, o[nf], 0, 0, 0);
      }
    }
  };

  std::integral_constant<int, 0> P0;
  std::integral_constant<int, 1> P1;

  issue(P0, 0);
  issue(P1, 1);
  lwrite(P0, 0);
  bar();

  for (int t = 0; t <= lastkt; t += 2) {
    issue(P0, t + 2);
    compute(P0, t);
    lwrite(P1, t + 1);
    bar();
    if (t + 1 <= lastkt) {
      issue(P1, t + 3);
      compute(P1, t + 1);
      lwrite(P0, t + 2);
      bar();
    }
  }

  const float inv = 1.0f / l_run;
#pragma unroll
  for (int r = 0; r < 4; ++r) {
    float ivr = __shfl(inv, 4 * g + r);
    long orow = ((long)b * TT + q0 + 16 * g + 4 * r + w) * HH;
#pragma unroll
    for (int nf = 0; nf < 6; ++nf) out[orow + nf * 16 + c] = o[nf][r] * ivr;
  }
}

extern "C" void kernel_launch(void* const* d_in, const int* in_sizes, int n_in,
                              void* d_out, int out_size, void* d_ws, size_t ws_size,
                              hipStream_t stream) {
  const float* x  = (const float*)d_in[0];
  const float* Wk = (const float*)d_in[1];
  const float* Wq = (const float*)d_in[2];
  const float* Wv = (const float*)d_in[3];
  float* out = (float*)d_out;

  unsigned short* Wt = (unsigned short*)d_ws;        // 3*96*768 bf16 = 442 KB
  unsigned short* Qb = Wt + 3 * HH * DD;             // [B*T][96] bf16
  unsigned short* Kb = Qb + (long)BB * TT * HH;      // [B*T][96] bf16
  unsigned short* Vt = Kb + (long)BB * TT * HH;      // [B][96][T] bf16 (transposed)

  wconv<<<dim3((3 * HH * DD + 255) / 256), dim3(256), 0, stream>>>(Wk, Wq, Wv, Wt);
  qkv_proj<<<dim3(BB * TT / 64), dim3(384), 0, stream>>>(x, Wt, Qb, Kb, Vt);
  attn<<<dim3(512), dim3(256), 0, stream>>>(Qb, Kb, Vt, out);
}